// Round 6
// baseline (309.645 us; speedup 1.0000x reference)
//
#include <hip/hip_runtime.h>

// conv2d 3x3 s1 p1, NCHW fp32, N=16 C=K=64 H=W=224. Implicit GEMM bf16 MFMA 16x16x32.
// wprep: wgt fp32 [64oc][64c][3][3] -> bf16 [18 ks][4 kb][64 oc][8 j] (ks: tap=ks>>1,
//   ch=ks&1; c = ch*32 + kb*8 + j) in d_ws.
// conv: 896 blocks x 256 thr. 4 waves = 4 oc-quarters (16 oc each), ALL waves compute
//   the same 4 output rows/iter (28-row chunk, 7 iters). 10-slot LDS row ring
//   (43.5 KB -> 3 blocks/CU), XOR swizzle. Per wave: 18 A-frags resident (72 VGPR),
//   acc 32, ~165 total -> 3 waves/SIMD target. 12 MMA groups/iter, each 6 ds_read_b128
//   + 12 MFMA (4 rows x 3 dh reuse). Staging: depth-2 rotating row loads (8 dwords),
//   halo split across 128 threads; ONE barrier per iter (read/write slots disjoint).

#define HH 224
#define WW 224
#define CHW (HH * WW)
#define PLANE 4352      // 34 w * 64 c * 2 B
#define NSLOT 10

typedef short bf16x4 __attribute__((ext_vector_type(4)));
typedef short bf16x8 __attribute__((ext_vector_type(8)));
typedef float f32x4  __attribute__((ext_vector_type(4)));

__device__ __forceinline__ unsigned short f2bf(float f) {
    union { float f; unsigned int u; } v; v.f = f;
    unsigned int u = v.u;
    return (unsigned short)((u + 0x7fffu + ((u >> 16) & 1u)) >> 16);  // RNE
}

#define SGB  __builtin_amdgcn_sched_group_barrier
#define MF16 __builtin_amdgcn_mfma_f32_16x16x32_bf16

__global__ void wprep_kernel(const float* __restrict__ wgt, unsigned short* __restrict__ wb) {
    const int i = blockIdx.x * 256 + threadIdx.x;
    if (i >= 36864) return;
    const int j  = i & 7;
    const int oc = (i >> 3) & 63;
    const int kb = (i >> 9) & 3;
    const int ks = i >> 11;          // 0..17
    const int tap = ks >> 1;
    const int c   = (ks & 1) * 32 + kb * 8 + j;
    wb[i] = f2bf(wgt[(oc * 64 + c) * 9 + tap]);
}

// One MMA group: wt (w-tile 0/1), dw (0..2), ch (0/1). 6 ds_read_b128 + 12 MFMA.
// Output row r uses input row hb-1+(r+dh) => B[r+dh]. Acc names cR##wt.
#define GRP(wt, dw, ch) do {                                                   \
    const int wl_ = (wt) * 16 + l15 + (dw);                                    \
    const char* p_ = ldsB + wl_ * 128 + (((ch) * 64 + kb16) ^ ((wl_ & 7) << 4)); \
    const bf16x8 B0 = *(const bf16x8*)(p_ + sl0);                              \
    const bf16x8 B1 = *(const bf16x8*)(p_ + sl1);                              \
    const bf16x8 B2 = *(const bf16x8*)(p_ + sl2);                              \
    const bf16x8 B3 = *(const bf16x8*)(p_ + sl3);                              \
    const bf16x8 B4 = *(const bf16x8*)(p_ + sl4);                              \
    const bf16x8 B5 = *(const bf16x8*)(p_ + sl5);                              \
    c0##wt = MF16(wfrag[(dw) * 2 + (ch)], B0, c0##wt, 0, 0, 0);                \
    c1##wt = MF16(wfrag[(dw) * 2 + (ch)], B1, c1##wt, 0, 0, 0);                \
    c2##wt = MF16(wfrag[(dw) * 2 + (ch)], B2, c2##wt, 0, 0, 0);                \
    c3##wt = MF16(wfrag[(dw) * 2 + (ch)], B3, c3##wt, 0, 0, 0);                \
    c0##wt = MF16(wfrag[(3 + (dw)) * 2 + (ch)], B1, c0##wt, 0, 0, 0);          \
    c1##wt = MF16(wfrag[(3 + (dw)) * 2 + (ch)], B2, c1##wt, 0, 0, 0);          \
    c2##wt = MF16(wfrag[(3 + (dw)) * 2 + (ch)], B3, c2##wt, 0, 0, 0);          \
    c3##wt = MF16(wfrag[(3 + (dw)) * 2 + (ch)], B4, c3##wt, 0, 0, 0);          \
    c0##wt = MF16(wfrag[(6 + (dw)) * 2 + (ch)], B2, c0##wt, 0, 0, 0);          \
    c1##wt = MF16(wfrag[(6 + (dw)) * 2 + (ch)], B3, c1##wt, 0, 0, 0);          \
    c2##wt = MF16(wfrag[(6 + (dw)) * 2 + (ch)], B4, c2##wt, 0, 0, 0);          \
    c3##wt = MF16(wfrag[(6 + (dw)) * 2 + (ch)], B5, c3##wt, 0, 0, 0);          \
    SGB(0x100, 6, 0); SGB(0x008, 12, 0);                                       \
} while (0)

#define STI(k, PV) do { if (st) {                                              \
    const int r_ = hb + 5 + (k);                                               \
    const bool ok_ = (r_ < HH);                                                \
    _Pragma("unroll")                                                          \
    for (int j = 0; j < 8; ++j) PV[j] = ok_ ? pxm[j * CHW + r_ * WW] : 0.f;    \
} } while (0)

#define STW(k, PV) do { if (st) {                                              \
    bf16x8 f_;                                                                 \
    _Pragma("unroll")                                                          \
    for (int j = 0; j < 8; ++j) f_[j] = (short)f2bf(PV[j]);                    \
    *(bf16x8*)(ldsB + ((hb + 5 + (k)) % NSLOT) * PLANE + lom) = f_;            \
} } while (0)

__global__ __launch_bounds__(256, 3)
void conv3x3_mfma(const float* __restrict__ x, const unsigned short* __restrict__ wb,
                  float* __restrict__ out) {
    __shared__ __align__(16) unsigned short lds[NSLOT * 34 * 64];  // 43520 B
    char* ldsB = (char*)lds;

    const int tid  = threadIdx.x;
    const int lane = tid & 63;
    const int wq   = tid >> 6;      // oc quarter (16 oc)
    const int l15  = lane & 15;     // A: oc-within-16; B/C: w/col
    const int kb   = lane >> 4;     // k-block 0..3
    const int kb16 = kb * 16;

    const int bid = blockIdx.x;
    const int n   = bid / 56;
    const int rem = bid % 56;
    const int ws  = rem / 8;
    const int hc  = rem % 8;
    const int wbase = ws * 32;
    const int h0    = hc * 28;

    // ---- A-frags: 18 resident (72 VGPR) ----
    const unsigned short* wlp = wb + kb * 512 + (wq * 16 + l15) * 8;
    bf16x8 wfrag[18];
#pragma unroll
    for (int ks = 0; ks < 18; ++ks)
        wfrag[ks] = *(const bf16x8*)(wlp + ks * 2048);

    // ---- prologue: stage rows h0-1 .. h0+4 ----
    for (int p = tid; p < 6 * 272; p += 256) {
        const int rrel = p / 272;
        const int q  = p % 272;
        const int c8 = q / 34;
        const int wl = q % 34;
        const int r  = h0 - 1 + rrel;
        const int gw = wbase - 1 + wl;
        bf16x8 f = {};
        if (r >= 0 && r < HH && gw >= 0 && gw < WW) {
            const float* px = x + (n * 64 + c8 * 8) * CHW + r * WW + gw;
#pragma unroll
            for (int j = 0; j < 8; ++j) f[j] = (short)f2bf(px[j * CHW]);
        }
        *(bf16x8*)(ldsB + ((r + NSLOT) % NSLOT) * PLANE + wl * 128
                   + ((c8 * 16) ^ ((wl & 7) << 4))) = f;
    }

    // ---- staging coords: main (interior) ----
    const int c8m = tid >> 5;
    const int wlm = 1 + (tid & 31);
    const float* pxm = x + (n * 64 + c8m * 8) * CHW + (wbase + (tid & 31));
    const int lom = wlm * 128 + ((c8m * 16) ^ ((wlm & 7) << 4));
    // ---- halo: tid<128: row hrow=tid>>5, edge e, 4 channels ----
    const int hrow = tid >> 5;            // 0..3 (valid only tid<128)
    const int eh   = (tid >> 4) & 1;
    const int c4h  = ((tid >> 1) & 7) * 8 + (tid & 1) * 4;
    const int wlh  = eh ? 33 : 0;
    const int gwh  = wbase - 1 + wlh;
    const bool hokw = (gwh >= 0 && gwh < WW);
    const float* pxh = x + (n * 64 + c4h) * CHW + gwh;
    const int loh = wlh * 128 + ((c4h * 2) ^ ((wlh & 7) << 4));

    __syncthreads();

#pragma unroll 1
    for (int it = 0; it < 7; ++it) {
        const int hb = h0 + 4 * it;
        const bool st = (it < 6);

        int t_ = (hb - 1 + 2 * NSLOT) % NSLOT;
        const int sl0 = t_ * PLANE; t_ = (t_ + 1 == NSLOT) ? 0 : t_ + 1;
        const int sl1 = t_ * PLANE; t_ = (t_ + 1 == NSLOT) ? 0 : t_ + 1;
        const int sl2 = t_ * PLANE; t_ = (t_ + 1 == NSLOT) ? 0 : t_ + 1;
        const int sl3 = t_ * PLANE; t_ = (t_ + 1 == NSLOT) ? 0 : t_ + 1;
        const int sl4 = t_ * PLANE; t_ = (t_ + 1 == NSLOT) ? 0 : t_ + 1;
        const int sl5 = t_ * PLANE;

        float pv0[8], pv1[8], hv[4];
        f32x4 c00 = {}, c01 = {}, c10 = {}, c11 = {};
        f32x4 c20 = {}, c21 = {}, c30 = {}, c31 = {};

        STI(0, pv0); STI(1, pv1);
        if (st && tid < 128) {
            const int r_ = hb + 5 + hrow;
            const bool ok_ = (r_ < HH) && hokw;
#pragma unroll
            for (int i = 0; i < 4; ++i) hv[i] = ok_ ? pxh[i * CHW + r_ * WW] : 0.f;
        }

        GRP(0, 0, 0); GRP(0, 0, 1); STW(0, pv0); STI(2, pv0);
        GRP(0, 1, 0); GRP(0, 1, 1); STW(1, pv1); STI(3, pv1);
        GRP(0, 2, 0); GRP(0, 2, 1); STW(2, pv0);
        GRP(1, 0, 0); GRP(1, 0, 1); STW(3, pv1);
        if (st && tid < 128) {
            bf16x4 fh_;
#pragma unroll
            for (int i = 0; i < 4; ++i) fh_[i] = (short)f2bf(hv[i]);
            *(bf16x4*)(ldsB + ((hb + 5 + hrow) % NSLOT) * PLANE + loh) = fh_;
        }

        // C layout per wave: col = l15 (w), row(oc) = kb*4 + reg
        float* po = out + (n * 64 + wq * 16 + kb * 4) * CHW + hb * WW + wbase + l15;

        GRP(1, 1, 0); GRP(1, 1, 1);
#pragma unroll
        for (int reg = 0; reg < 4; ++reg) {
            po[reg * CHW + 0 * WW] = c00[reg];
            po[reg * CHW + 1 * WW] = c10[reg];
            po[reg * CHW + 2 * WW] = c20[reg];
            po[reg * CHW + 3 * WW] = c30[reg];
        }

        GRP(1, 2, 0); GRP(1, 2, 1);
#pragma unroll
        for (int reg = 0; reg < 4; ++reg) {
            po[reg * CHW + 0 * WW + 16] = c01[reg];
            po[reg * CHW + 1 * WW + 16] = c11[reg];
            po[reg * CHW + 2 * WW + 16] = c21[reg];
            po[reg * CHW + 3 * WW + 16] = c31[reg];
        }

        __syncthreads();  // rows hb+5..hb+8 visible; prev-iter read slots now reusable
    }
}

extern "C" void kernel_launch(void* const* d_in, const int* in_sizes, int n_in,
                              void* d_out, int out_size, void* d_ws, size_t ws_size,
                              hipStream_t stream) {
    const float* x   = (const float*)d_in[0];
    const float* wgt = (const float*)d_in[1];
    float* out       = (float*)d_out;
    unsigned short* wbuf = (unsigned short*)d_ws;  // 73728 B needed

    wprep_kernel<<<dim3(144), dim3(256), 0, stream>>>(wgt, wbuf);
    conv3x3_mfma<<<dim3(16 * 7 * 8), dim3(256), 0, stream>>>(x, wbuf, out);
}

// Round 8
// 177.537 us; speedup vs baseline: 1.7441x; 1.7441x over previous
//
#include <hip/hip_runtime.h>

// conv2d 3x3 s1 p1, NCHW fp32, N=16 C=K=64 H=W=224. Implicit GEMM bf16 MFMA 32x32x16.
// R4 structure (best, 177us) + ONE change: __syncthreads() -> lgkmcnt(0)+raw s_barrier
// (no vmcnt drain; C stores and prefetch loads stay in flight across iterations, T3/T4).
// (R7 halo-pointer typo fixed: pxh channel base is c8h*8, matching loh.)
// wprep: wgt fp32 [64][64][3][3] -> bf16 K-major [36 ks][2 g][64 oc][8 c] in d_ws.
// conv: 448 blocks x 256 thr (4 waves = 2 oc-halves x 2 row-groups), 4 rows/wave,
//   8 output rows/iter, 7 iters per 56-row chunk. 18-slot LDS ring (76.5 KB, 2 blk/CU).
//   Weights dh0/dh1 resident (96 VGPR); dh2 streamed from L2 (ping-pong).
//   8 staging batches/iter interleaved with 6 MMA sections; 1 barrier/iter.

#define HH 224
#define WW 224
#define CHW (HH * WW)
#define PLANE 4352      // 34 w * 64 c * 2 B
#define NSLOT 18

typedef short bf16x8 __attribute__((ext_vector_type(8)));
typedef float f32x16 __attribute__((ext_vector_type(16)));

__device__ __forceinline__ unsigned short f2bf(float f) {
    union { float f; unsigned int u; } v; v.f = f;
    unsigned int u = v.u;
    return (unsigned short)((u + 0x7fffu + ((u >> 16) & 1u)) >> 16);  // RNE
}

#define SGB  __builtin_amdgcn_sched_group_barrier
#define MFMA __builtin_amdgcn_mfma_f32_32x32x16_bf16

// Workgroup fence: LDS writes visible to all waves, but NO vmcnt drain --
// global stores/loads stay in flight across the barrier (T3/T4 counted-wait idiom).
__device__ __forceinline__ void block_fence_lds() {
    asm volatile("s_waitcnt lgkmcnt(0)" ::: "memory");
    __builtin_amdgcn_s_barrier();
    __builtin_amdgcn_sched_barrier(0);
}

__global__ void wprep_kernel(const float* __restrict__ wgt, unsigned short* __restrict__ wb) {
    const int i = blockIdx.x * 256 + threadIdx.x;
    if (i >= 36864) return;
    const int j   = i & 7;
    const int oc  = (i >> 3) & 63;
    const int g   = (i >> 9) & 1;
    const int ks  = i >> 10;
    const int tap = ks >> 2;
    const int c   = (ks & 3) * 16 + g * 8 + j;
    wb[i] = f2bf(wgt[(oc * 64 + c) * 9 + tap]);
}

// 6 ds_read_b128 + 12 MFMA (4 rows x 3 dh) for one (dw, cq); all indices literal.
#define MMA_CQ(dw, cq, WFU) do {                                              \
    const int off_ = (((cq) * 32 + g16) ^ swz_);                              \
    const bf16x8 B0 = *(const bf16x8*)(ldsB + sl0 + wb_ + off_);              \
    const bf16x8 B1 = *(const bf16x8*)(ldsB + sl1 + wb_ + off_);              \
    const bf16x8 B2 = *(const bf16x8*)(ldsB + sl2 + wb_ + off_);              \
    const bf16x8 B3 = *(const bf16x8*)(ldsB + sl3 + wb_ + off_);              \
    const bf16x8 B4 = *(const bf16x8*)(ldsB + sl4 + wb_ + off_);              \
    const bf16x8 B5 = *(const bf16x8*)(ldsB + sl5 + wb_ + off_);              \
    a0 = MFMA(wfrag[(dw)*4 + (cq)], B0, a0, 0, 0, 0);                         \
    a1 = MFMA(wfrag[(dw)*4 + (cq)], B1, a1, 0, 0, 0);                         \
    a2 = MFMA(wfrag[(dw)*4 + (cq)], B2, a2, 0, 0, 0);                         \
    a3 = MFMA(wfrag[(dw)*4 + (cq)], B3, a3, 0, 0, 0);                         \
    a0 = MFMA(wfrag[12 + (dw)*4 + (cq)], B1, a0, 0, 0, 0);                    \
    a1 = MFMA(wfrag[12 + (dw)*4 + (cq)], B2, a1, 0, 0, 0);                    \
    a2 = MFMA(wfrag[12 + (dw)*4 + (cq)], B3, a2, 0, 0, 0);                    \
    a3 = MFMA(wfrag[12 + (dw)*4 + (cq)], B4, a3, 0, 0, 0);                    \
    a0 = MFMA(WFU, B2, a0, 0, 0, 0);                                          \
    a1 = MFMA(WFU, B3, a1, 0, 0, 0);                                          \
    a2 = MFMA(WFU, B4, a2, 0, 0, 0);                                          \
    a3 = MFMA(WFU, B5, a3, 0, 0, 0);                                          \
    SGB(0x100, 6, 0); SGB(0x008, 12, 0);                                      \
} while (0)

// One section = 2 cq of one dw; first issues NEXT section's dh2 frags (ping-pong).
#define SECTION(dw, cqp, WFU0, WFU1, WFLD0, WFLD1, ldw, lcqp) do {            \
    WFLD0 = *(const bf16x8*)(wlane + ((6 + (ldw))*4 + 2*(lcqp)    ) * 1024);  \
    WFLD1 = *(const bf16x8*)(wlane + ((6 + (ldw))*4 + 2*(lcqp) + 1) * 1024);  \
    const int wl_  = s + (dw);                                                \
    const int swz_ = (wl_ & 7) << 4;                                          \
    const int wb_  = wl_ * 128;                                               \
    MMA_CQ(dw, 2*(cqp),     WFU0);                                            \
    MMA_CQ(dw, 2*(cqp) + 1, WFU1);                                            \
} while (0)

#define STI(k) do { if (st) {                                                 \
    const int r_ = h + 9 + (k);                                               \
    const bool ok_ = (r_ < HH);                                               \
    _Pragma("unroll")                                                         \
    for (int j = 0; j < 8; ++j) pv[j] = ok_ ? pxm[j*CHW + r_*WW] : 0.f;       \
    if (tid >= 240) {                                                         \
        const bool okh_ = ok_ && hokw;                                        \
        _Pragma("unroll")                                                     \
        for (int j = 0; j < 8; ++j) hv[j] = okh_ ? pxh[j*CHW + r_*WW] : 0.f;  \
    } } } while (0)

#define STW(k) do { if (st) {                                                 \
    int sw_ = slw + (k); if (sw_ >= NSLOT) sw_ -= NSLOT;                      \
    bf16x8 f_;                                                                \
    _Pragma("unroll")                                                         \
    for (int j = 0; j < 8; ++j) f_[j] = (short)f2bf(pv[j]);                   \
    *(bf16x8*)(ldsB + sw_ * PLANE + lom) = f_;                                \
    if (tid >= 240) {                                                         \
        bf16x8 fh_;                                                           \
        _Pragma("unroll")                                                     \
        for (int j = 0; j < 8; ++j) fh_[j] = (short)f2bf(hv[j]);              \
        *(bf16x8*)(ldsB + sw_ * PLANE + loh) = fh_;                           \
    } } } while (0)

__global__ __launch_bounds__(256, 2)
void conv3x3_mfma(const float* __restrict__ x, const unsigned short* __restrict__ wb,
                  float* __restrict__ out) {
    __shared__ __align__(16) unsigned short lds[NSLOT * 34 * 64];  // 78336 B
    char* ldsB = (char*)lds;

    const int tid  = threadIdx.x;
    const int lane = tid & 63;
    const int wv   = tid >> 6;
    const int och  = wv & 1;   // oc half
    const int rg4  = wv >> 1;  // row group (4 rows each)
    const int s    = lane & 31;
    const int g    = lane >> 5;
    const int g16  = g * 16;

    const int bid = blockIdx.x;
    const int n   = bid / 28;
    const int rem = bid % 28;
    const int ws  = rem / 4;
    const int hc  = rem % 4;
    const int wbase = ws * 32;
    const int h0    = hc * 56;

    // ---- weights: dh0/dh1 resident (24 frags), dh2 ping-pong stream ----
    const unsigned short* wlane = wb + g * 512 + (och * 32 + s) * 8;
    bf16x8 wfrag[24];
#pragma unroll
    for (int ks = 0; ks < 24; ++ks)
        wfrag[ks] = *(const bf16x8*)(wlane + ks * 1024);
    bf16x8 wfA0 = *(const bf16x8*)(wlane + 24 * 1024);
    bf16x8 wfA1 = *(const bf16x8*)(wlane + 25 * 1024);
    bf16x8 wfB0 = {}, wfB1 = {};

    // ---- prologue: stage rows h0-1 .. h0+8 ----
    for (int p = tid; p < 10 * 272; p += 256) {
        const int rrel = p / 272;
        const int q  = p % 272;
        const int c8 = q / 34;
        const int wl = q % 34;
        const int r  = h0 - 1 + rrel;
        const int gw = wbase - 1 + wl;
        bf16x8 f = {};
        if (r >= 0 && r < HH && gw >= 0 && gw < WW) {
            const float* px = x + (n * 64 + c8 * 8) * CHW + r * WW + gw;
#pragma unroll
            for (int j = 0; j < 8; ++j) f[j] = (short)f2bf(px[j * CHW]);
        }
        *(bf16x8*)(ldsB + ((r + NSLOT) % NSLOT) * PLANE + wl * 128
                   + ((c8 * 16) ^ ((wl & 7) << 4))) = f;
    }

    // ---- staging coords ----
    const int c8m = tid >> 5;
    const int wlm = 1 + (tid & 31);
    const float* pxm = x + (n * 64 + c8m * 8) * CHW + (wbase + (tid & 31));
    const int lom = wlm * 128 + ((c8m * 16) ^ ((wlm & 7) << 4));
    // halo: tid 240..255 -> lane 48..63: c8 = lane&7, wl = 0 or 33
    const int c8h = lane & 7;
    const int wlh = ((lane >> 3) & 1) * 33;
    const int gwh = wbase - 1 + wlh;
    const bool hokw = (gwh >= 0 && gwh < WW);
    const float* pxh = x + (n * 64 + c8h * 8) * CHW + gwh;
    const int loh = wlh * 128 + ((c8h * 16) ^ ((wlh & 7) << 4));

    block_fence_lds();

#pragma unroll 1
    for (int it = 0; it < 7; ++it) {
        const int h  = h0 + 8 * it;
        const int hb = h + 4 * rg4;
        const bool st = (it < 6);
        const int slw = (h + 9) % NSLOT;

        int t_ = (hb - 1 + NSLOT) % NSLOT;
        const int sl0 = t_ * PLANE; t_ = (t_ + 1 == NSLOT) ? 0 : t_ + 1;
        const int sl1 = t_ * PLANE; t_ = (t_ + 1 == NSLOT) ? 0 : t_ + 1;
        const int sl2 = t_ * PLANE; t_ = (t_ + 1 == NSLOT) ? 0 : t_ + 1;
        const int sl3 = t_ * PLANE; t_ = (t_ + 1 == NSLOT) ? 0 : t_ + 1;
        const int sl4 = t_ * PLANE; t_ = (t_ + 1 == NSLOT) ? 0 : t_ + 1;
        const int sl5 = t_ * PLANE;

        float pv[8], hv[8];
        f32x16 a0 = {}, a1 = {}, a2 = {}, a3 = {};

        STI(0); SECTION(0, 0, wfA0, wfA1, wfB0, wfB1, 0, 1); STW(0);
        STI(1); SECTION(0, 1, wfB0, wfB1, wfA0, wfA1, 1, 0); STW(1);
        STI(2); SECTION(1, 0, wfA0, wfA1, wfB0, wfB1, 1, 1); STW(2);
        STI(3); SECTION(1, 1, wfB0, wfB1, wfA0, wfA1, 2, 0); STW(3);
        STI(4); SECTION(2, 0, wfA0, wfA1, wfB0, wfB1, 2, 1); STW(4);
        STI(5); SECTION(2, 1, wfB0, wfB1, wfA0, wfA1, 0, 0); STW(5);

        // ---- C stores: rows hb..hb+3 (col = s = w; row = (rg&3)+8*(rg>>2)+4g = oc) ----
        float* po = out + (n * 64 + och * 32 + 4 * g) * CHW + hb * WW + wbase + s;
        STI(6);
#pragma unroll
        for (int rg = 0; rg < 16; ++rg) {
            const int o_ = ((rg & 3) + 8 * (rg >> 2)) * CHW;
            po[o_]      = a0[rg];
            po[o_ + WW] = a1[rg];
        }
        STW(6); STI(7);
#pragma unroll
        for (int rg = 0; rg < 16; ++rg) {
            const int o_ = ((rg & 3) + 8 * (rg >> 2)) * CHW;
            po[o_ + 2 * WW] = a2[rg];
            po[o_ + 3 * WW] = a3[rg];
        }
        STW(7);

        block_fence_lds();  // LDS writes h+9..h+16 visible; stores/loads stay in flight
    }
}

extern "C" void kernel_launch(void* const* d_in, const int* in_sizes, int n_in,
                              void* d_out, int out_size, void* d_ws, size_t ws_size,
                              hipStream_t stream) {
    const float* x   = (const float*)d_in[0];
    const float* wgt = (const float*)d_in[1];
    float* out       = (float*)d_out;
    unsigned short* wbuf = (unsigned short*)d_ws;  // 73728 B needed

    wprep_kernel<<<dim3(144), dim3(256), 0, stream>>>(wgt, wbuf);
    conv3x3_mfma<<<dim3(448), dim3(256), 0, stream>>>(x, wbuf, out);
}